// Round 7
// baseline (286.465 us; speedup 1.0000x reference)
//
#include <hip/hip_runtime.h>

#define TT   2048
#define CC   256
#define LL   256
#define SS   513            // 2*LL+1
#define TM   1023           // meet point: fwd -> alpha[TM], bwd -> gamma[TM+1]
#define EPSF (1e-7f)
#define LN2F (0.69314718055994531f)
#define RING 10             // LDS row ring slots per wave
#define RD   8              // stage distance (rows ahead)
#define RBTH 64             // rebase threshold (bits)
#define EMINI (-2000000000)

#if __has_builtin(__builtin_amdgcn_frexp_expf)
#define FREXP_EXP __builtin_amdgcn_frexp_expf
#else
static __device__ __forceinline__ int FREXP_EXP(float x){ int e; frexpf(x,&e); return e; }
#endif
#if __has_builtin(__builtin_amdgcn_ldexpf)
#define LDEXP __builtin_amdgcn_ldexpf
#else
#define LDEXP ldexpf
#endif

// async stage: 64 lanes x 16B = one full 1KB probability row -> LDS slot.
// LDS dest is wave-uniform base + lane*16 (HW rule); global src is per-lane.
__device__ __forceinline__ void stage16(const float* g, float* l)
{
    __builtin_amdgcn_global_load_lds(
        (const __attribute__((address_space(1))) unsigned int*)g,
        (__attribute__((address_space(3))) unsigned int*)l,
        16, 0, 0);
}

// Block = 128 threads (2 waves) per batch.
//   wave 0: forward alpha DP, rows 1..TM       (init row 0)
//   wave 1: backward gamma DP, rows TT-2..TM+1 (init row TT-1)
// Lane l owns cells s = 8l..8l+7 plus shadow f[8] (cell 8(l+1); real 512 on
// lane 63). Even s = blank, odd s = label 4l+i. Extended-range floats:
// value = f[j]*2^e (one e per lane), renorm every ~4 steps.
// Rows are staged into a per-wave 10-slot LDS ring, RD=8 ahead, with counted
// vmcnt(6) waits; per-step consumption is 5 ds_read (prefetched 1 step).

__launch_bounds__(128, 1)
__global__ void ctc_mim_kernel(const int* __restrict__ y_true,
                               const float* __restrict__ y_pred,
                               float* __restrict__ out)
{
    __shared__ float ring[2][RING][CC];
    __shared__ float cw[SS];   // beta[TM][s] combo mantissas (per-lane scale)
    __shared__ int   ew[64];   // bwd per-lane exponent

    const int tid   = threadIdx.x;
    const int w     = tid >> 6;          // 0 = fwd, 1 = bwd (wave-uniform)
    const int lane  = tid & 63;
    const int b     = blockIdx.x;
    const int blank = CC - 1;

    const int*   lab  = y_true + b * LL;
    const float* base = y_pred + (size_t)b * TT * CC;

    // label columns for odd cells j = 2i+1 (label index 4*lane + i)
    int   col[4];
    float kup[4];    // fwd skip legality into cell s (allow2[s])
    float kdn[4];    // bwd skip legality out of cell s (allow2[s+2])
    #pragma unroll
    for (int i = 0; i < 4; ++i) {
        const int li = 4 * lane + i;               // 0..255
        const int z  = lab[li];
        col[i] = z;
        const int zm = (li >= 1) ? lab[li - 1] : -1;
        kup[i] = (z != zm) ? 1.0f : 0.0f;
        kdn[i] = (li <= 254 && lab[li + 1] != z) ? 1.0f : 0.0f;
    }

    float f[9];
    #pragma unroll
    for (int j = 0; j < 9; ++j) f[j] = 0.0f;
    int  e = 0;
    bool lzero;

    if (w == 0) {
        if (lane == 0) {
            f[0] = base[blank]  + EPSF;            // s=0, t=0
            f[1] = base[col[0]] + EPSF;            // s=1, t=0
        }
        lzero = (lane != 0);
    } else {
        if (lane == 63) {
            const float* rT = base + (size_t)(TT - 1) * CC;
            f[7] = rT[col[3]] + EPSF;              // s=511, t=TT-1
            f[8] = rT[blank]  + EPSF;              // s=512 (shadow), t=TT-1
        }
        lzero = (lane != 63);
    }

    auto renorm = [&]() {
        float m = fmaxf(fmaxf(fmaxf(f[0], f[1]), fmaxf(f[2], f[3])),
                        fmaxf(fmaxf(f[4], f[5]), fmaxf(f[6], fmaxf(f[7], f[8]))));
        const int em = FREXP_EXP(m);               // frexp_exp(0) == 0
        #pragma unroll
        for (int j = 0; j < 9; ++j) f[j] = LDEXP(f[j], -em);
        e += em;
    };

    auto fwd_step = [&](float pb, float p0, float p1, float p2, float p3) {
        float u7 = __shfl_up(f[7], 1);
        int   ue = __shfl_up(e, 1);
        if (lane == 0) { u7 = 0.0f; ue = e; }
        int dlt = ue - e;
        const bool rb = lzero || (dlt >= RBTH);
        if (__ballot(rb)) {                        // rare: front / scale jump
            const int sh = rb ? -dlt : 0;
            #pragma unroll
            for (int j = 0; j < 9; ++j) f[j] = LDEXP(f[j], sh);
            e   = rb ? ue : e;
            dlt = rb ? 0  : dlt;
            lzero = lzero && (u7 == 0.0f);
        }
        const float bf = LDEXP(u7, dlt);
        const float n0 = (f[0] + bf) * pb;
        const float n1 = (f[1] + f[0] + bf   * kup[0]) * p0;
        const float n2 = (f[2] + f[1]) * pb;
        const float n3 = (f[3] + f[2] + f[1] * kup[1]) * p1;
        const float n4 = (f[4] + f[3]) * pb;
        const float n5 = (f[5] + f[4] + f[3] * kup[2]) * p2;
        const float n6 = (f[6] + f[5]) * pb;
        const float n7 = (f[7] + f[6] + f[5] * kup[3]) * p3;
        const float n8 = (f[8] + f[7]) * pb;
        f[0]=n0; f[1]=n1; f[2]=n2; f[3]=n3; f[4]=n4;
        f[5]=n5; f[6]=n6; f[7]=n7; f[8]=n8;
    };

    auto bwd_step = [&](float pb, float p0, float p1, float p2, float p3) {
        float d1 = __shfl_down(f[1], 1);
        int   de = __shfl_down(e, 1);
        if (lane == 63) { d1 = 0.0f; de = e; }
        int dlt = de - e;
        const bool rb = lzero || (dlt >= RBTH);
        if (__ballot(rb)) {
            const int sh = rb ? -dlt : 0;
            #pragma unroll
            for (int j = 0; j < 9; ++j) f[j] = LDEXP(f[j], sh);
            e   = rb ? de : e;
            dlt = rb ? 0  : dlt;
            lzero = lzero && (d1 == 0.0f);
        }
        const float bf = LDEXP(d1, dlt);
        const float n0 = (f[0] + f[1]) * pb;
        const float n1 = (f[1] + f[2] + f[3] * kdn[0]) * p0;
        const float n2 = (f[2] + f[3]) * pb;
        const float n3 = (f[3] + f[4] + f[5] * kdn[1]) * p1;
        const float n4 = (f[4] + f[5]) * pb;
        const float n5 = (f[5] + f[6] + f[7] * kdn[2]) * p2;
        const float n6 = (f[6] + f[7]) * pb;
        const float n7 = (f[7] + f[8] + bf   * kdn[3]) * p3;
        const float n8 = (f[8] + bf) * pb;
        f[0]=n0; f[1]=n1; f[2]=n2; f[3]=n3; f[4]=n4;
        f[5]=n5; f[6]=n6; f[7]=n7; f[8]=n8;
    };

#define LDPV(PV, SLOT) do {                                   \
        PV[0] = ring[w][(SLOT)][col[0]] + EPSF;               \
        PV[1] = ring[w][(SLOT)][col[1]] + EPSF;               \
        PV[2] = ring[w][(SLOT)][col[2]] + EPSF;               \
        PV[3] = ring[w][(SLOT)][col[3]] + EPSF;               \
        PV[4] = ring[w][(SLOT)][CC - 1] + EPSF;               \
    } while (0)

#define VMWAIT(N) do {                                        \
        asm volatile("s_waitcnt vmcnt(" #N ")" ::: "memory"); \
        __builtin_amdgcn_sched_barrier(0);                    \
    } while (0)

    float pvA[5], pvB[5];

    // prologue: stage rows for steps 0..RD-1 into slots 0..RD-1
    #pragma unroll
    for (int j = 0; j < RD; ++j) {
        const int r = (w == 0) ? (1 + j) : (TT - 2 - j);
        stage16(base + (size_t)r * CC + 4 * lane, &ring[w][j][0]);
    }
    VMWAIT(7);              // oldest stage (slot 0) complete
    LDPV(pvA, 0);

    if (w == 0) {
        for (int c = 0; c < 102; ++c) {          // steps t = 1 .. 1020
            const int tb = 1 + c * 10;
            #pragma unroll
            for (int k = 0; k < 10; ++k) {
                VMWAIT(6);                       // stage for step t+1 done
                if ((k & 1) == 0) LDPV(pvB, (k + 1) % RING);
                else              LDPV(pvA, (k + 1) % RING);
                int sr = tb + k + RD; if (sr > TM) sr = TM;
                stage16(base + (size_t)sr * CC + 4 * lane,
                        &ring[w][(k + RD) % RING][0]);
                if ((k & 1) == 0) fwd_step(pvA[4], pvA[0], pvA[1], pvA[2], pvA[3]);
                else              fwd_step(pvB[4], pvB[0], pvB[1], pvB[2], pvB[3]);
                if (k == 3 || k == 7) renorm();
            }
        }
        #pragma unroll
        for (int k = 0; k < 3; ++k) {            // tail t = 1021..1023
            VMWAIT(6);
            if ((k & 1) == 0) LDPV(pvB, (k + 1) % RING);
            else              LDPV(pvA, (k + 1) % RING);
            stage16(base + (size_t)TM * CC + 4 * lane,
                    &ring[w][(k + RD) % RING][0]);
            if ((k & 1) == 0) fwd_step(pvA[4], pvA[0], pvA[1], pvA[2], pvA[3]);
            else              fwd_step(pvB[4], pvB[0], pvB[1], pvB[2], pvB[3]);
        }
    } else {
        for (int c = 0; c < 102; ++c) {          // steps i = 0 .. 1019, row 2046-i
            const int ib = c * 10;
            #pragma unroll
            for (int k = 0; k < 10; ++k) {
                VMWAIT(6);
                if ((k & 1) == 0) LDPV(pvB, (k + 1) % RING);
                else              LDPV(pvA, (k + 1) % RING);
                int sr = (TT - 2) - (ib + k + RD); if (sr < TM + 1) sr = TM + 1;
                stage16(base + (size_t)sr * CC + 4 * lane,
                        &ring[w][(k + RD) % RING][0]);
                if ((k & 1) == 0) bwd_step(pvA[4], pvA[0], pvA[1], pvA[2], pvA[3]);
                else              bwd_step(pvB[4], pvB[0], pvB[1], pvB[2], pvB[3]);
                if (k == 3 || k == 7) renorm();
            }
        }
        #pragma unroll
        for (int k = 0; k < 3; ++k) {            // tail i = 1020..1022, rows 1026..1024
            VMWAIT(6);
            if ((k & 1) == 0) LDPV(pvB, (k + 1) % RING);
            else              LDPV(pvA, (k + 1) % RING);
            stage16(base + (size_t)(TM + 1) * CC + 4 * lane,
                    &ring[w][(k + RD) % RING][0]);
            if ((k & 1) == 0) bwd_step(pvA[4], pvA[0], pvA[1], pvA[2], pvA[3]);
            else              bwd_step(pvB[4], pvB[0], pvB[1], pvB[2], pvB[3]);
        }

        // combo: beta[TM][s] = g[s] + g[s+1] + allow2[s+2]*g[s+2] (no p mult)
        float d1 = __shfl_down(f[1], 1);
        int   de = __shfl_down(e, 1);
        if (lane == 63) { d1 = 0.0f; de = e; }
        int dlt = de - e;
        if (dlt >= RBTH) {                       // one-shot, per-lane safe
            #pragma unroll
            for (int j = 0; j < 9; ++j) f[j] = LDEXP(f[j], -dlt);
            e = de; dlt = 0;
        }
        const float bf = LDEXP(d1, dlt);
        float cb[9];
        cb[0] = f[0] + f[1];
        cb[1] = f[1] + f[2] + f[3] * kdn[0];
        cb[2] = f[2] + f[3];
        cb[3] = f[3] + f[4] + f[5] * kdn[1];
        cb[4] = f[4] + f[5];
        cb[5] = f[5] + f[6] + f[7] * kdn[2];
        cb[6] = f[6] + f[7];
        cb[7] = f[7] + f[8] + bf   * kdn[3];
        cb[8] = f[8] + bf;                        // combo[512] (lane 63: bf=0)

        #pragma unroll
        for (int j = 0; j < 8; ++j) cw[8 * lane + j] = cb[j];
        if (lane == 63) cw[512] = cb[8];
        ew[lane] = e;
    }

    __syncthreads();

    if (w == 0) {
        // lane l's 8 cells align exactly with bwd lane l's 8 cells
        float part = 0.0f;
        #pragma unroll
        for (int j = 0; j < 8; ++j) part += f[j] * cw[8 * lane + j];
        if (lane == 63) part += f[8] * cw[512];
        int   ep = (part > 0.0f) ? (e + ew[lane]) : EMINI;
        float m  = part;
        #pragma unroll
        for (int d = 1; d < 64; d <<= 1) {
            const float mo = __shfl_xor(m, d);
            const int   eo = __shfl_xor(ep, d);
            const int   E  = max(ep, eo);
            m  = LDEXP(m, ep - E) + LDEXP(mo, eo - E);
            ep = E;
        }
        if (lane == 0)
            out[b] = -LN2F * ((float)ep + __builtin_amdgcn_logf(m));
    }
}

extern "C" void kernel_launch(void* const* d_in, const int* in_sizes, int n_in,
                              void* d_out, int out_size, void* d_ws, size_t ws_size,
                              hipStream_t stream)
{
    const int*   y_true = (const int*)d_in[0];
    const float* y_pred = (const float*)d_in[1];
    float*       out    = (float*)d_out;
    const int B = in_sizes[0] / LL;   // 32
    ctc_mim_kernel<<<B, 128, 0, stream>>>(y_true, y_pred, out);
}

// Round 8
// 211.875 us; speedup vs baseline: 1.3520x; 1.3520x over previous
//
#include <hip/hip_runtime.h>

#define TT   2048
#define CC   256
#define LL   256
#define SS   513            // 2*LL+1
#define TM   1023           // meet point: fwd -> alpha[TM], bwd -> gamma[TM+1]
#define EPSF (1e-7f)
#define LN2F (0.69314718055994531f)
#define RING 12             // LDS row ring slots per wave (3 phases x 4)
#define EMINI (-2000000000)

#if __has_builtin(__builtin_amdgcn_frexp_expf)
#define FREXP_EXP __builtin_amdgcn_frexp_expf
#else
static __device__ __forceinline__ int FREXP_EXP(float x){ int e; frexpf(x,&e); return e; }
#endif
#if __has_builtin(__builtin_amdgcn_ldexpf)
#define LDEXP __builtin_amdgcn_ldexpf
#else
#define LDEXP ldexpf
#endif

// async stage: 64 lanes x 16B = one full 1KB probability row -> LDS slot
__device__ __forceinline__ void stage16(const float* g, float* l)
{
    __builtin_amdgcn_global_load_lds(
        (const __attribute__((address_space(1))) unsigned int*)g,
        (__attribute__((address_space(3))) unsigned int*)l,
        16, 0, 0);
}

#define VMWAIT(N) do {                                        \
        asm volatile("s_waitcnt vmcnt(" #N ")" ::: "memory"); \
        __builtin_amdgcn_sched_barrier(0);                    \
    } while (0)

// fwd sweep: cell i reads i-1, i-2 (old values) -> descending in-place
#define FWD_SWEEP(PVk, LO) do {                                              \
        _Pragma("unroll")                                                    \
        for (int i = 16; i >= (LO); --i) {                                   \
            if (i & 1) g[i] = (g[i] + g[i-1] + g[i-2]*kk[(i-1)>>1])          \
                              * (PVk)[(i-1)>>1];                             \
            else       g[i] = (g[i] + g[i-1]) * (PVk)[8];                    \
        }                                                                    \
    } while (0)

// bwd sweep: cell i reads i+1, i+2 (old values) -> ascending in-place
#define BWD_SWEEP(PVk, HI) do {                                              \
        _Pragma("unroll")                                                    \
        for (int i = 0; i <= (HI); ++i) {                                    \
            if (i & 1) g[i] = (g[i] + g[i+1] + g[i+2]*kk[(i-1)>>1])          \
                              * (PVk)[(i-1)>>1];                             \
            else       g[i] = (g[i] + g[i+1]) * (PVk)[8];                    \
        }                                                                    \
    } while (0)

// Block = 128 threads (2 waves) per batch.
//   wave 0: forward alpha DP, rows 1..TM       (init row 0)
//   wave 1: backward gamma DP, rows TT-2..TM+1 (init row TT-1)
// Lane l owns cells 8l..8l+7 + shadow (cell 8l+8). K=4 steps per group:
// one batched halo exchange (8 f + 1 e shfl) + exponent align, then 4
// lane-local stencil sweeps over g[17]. p-rows staged into a 12-slot LDS
// ring (vmcnt-counted, 2 groups in flight), 36 batched ds_reads per group.

__launch_bounds__(128, 1)
__global__ void ctc_grp_kernel(const int* __restrict__ y_true,
                               const float* __restrict__ y_pred,
                               float* __restrict__ out)
{
    __shared__ float ring[2][RING][CC];
    __shared__ float cw[SS];   // beta[TM][s] combo mantissas (per-lane scale)
    __shared__ int   ew[64];   // bwd per-lane exponent

    const int tid   = threadIdx.x;
    const int w     = tid >> 6;          // 0 = fwd, 1 = bwd (wave-uniform)
    const int lane  = tid & 63;
    const int b     = blockIdx.x;
    const int blank = CC - 1;

    const int*   lab  = y_true + b * LL;
    const float* base = y_pred + (size_t)b * TT * CC;

    // 8 label columns + skip legality for the 17-cell window
    int   cols[8];
    float kk[8];
    if (w == 0) {          // fwd: labels 4l-4 .. 4l+3, kk = allow2 into cell
        #pragma unroll
        for (int j = 0; j < 8; ++j) {
            const int li  = 4 * lane - 4 + j;
            const int lic = li < 0 ? 0 : li;
            const int z   = lab[lic];
            cols[j] = z;
            const int zm = (li >= 1) ? lab[li - 1] : -1;
            kk[j] = (li >= 0 && z != zm) ? 1.0f : 0.0f;
        }
    } else {               // bwd: labels 4l .. 4l+7, kk = allow2 out of cell
        #pragma unroll
        for (int j = 0; j < 8; ++j) {
            const int li  = 4 * lane + j;
            const int lic = li > 255 ? 255 : li;
            const int z   = lab[lic];
            cols[j] = z;
            kk[j] = (li <= 254 && lab[li + 1] != z) ? 1.0f : 0.0f;
        }
    }

    float f[9];
    #pragma unroll
    for (int j = 0; j < 9; ++j) f[j] = 0.0f;
    int  e = 0;
    bool mm;
    if (w == 0) {
        if (lane == 0) {
            f[0] = base[blank]   + EPSF;           // s=0, t=0
            f[1] = base[cols[4]] + EPSF;           // s=1 (label 4l+0), t=0
        }
        mm = (lane == 0);
    } else {
        if (lane == 63) {
            const float* rT = base + (size_t)(TT - 1) * CC;
            f[7] = rT[cols[3]] + EPSF;             // s=511 (label 255), t=TT-1
            f[8] = rT[blank]   + EPSF;             // s=512 (shadow), t=TT-1
        }
        mm = (lane == 63);
    }

    // prologue: stage first 8 rows (2 groups ahead)
    #pragma unroll
    for (int k = 0; k < 8; ++k) {
        const int r = (w == 0) ? (1 + k) : (TT - 2 - k);
        stage16(base + (size_t)r * CC + 4 * lane, &ring[w][k][0]);
    }

    if (w == 0) {
        int sb = 0, stb = 8;                       // read / stage slot bases
        for (int gI = 0; gI < 255; ++gI) {
            VMWAIT(4);                             // this group's 4 rows ready
            #pragma unroll
            for (int k = 0; k < 4; ++k) {          // stage rows 2 groups out
                int ci = 4 * gI + 8 + k; if (ci > 1022) ci = 1022;
                stage16(base + (size_t)(1 + ci) * CC + 4 * lane,
                        &ring[0][stb + k][0]);
            }
            // ---- exchange + align (the ONLY cross-lane point) ----
            float h[8];
            #pragma unroll
            for (int j = 0; j < 8; ++j) h[j] = __shfl_up(f[j], 1);
            int he = __shfl_up(e, 1);
            if (lane == 0) {
                he = e;
                #pragma unroll
                for (int j = 0; j < 8; ++j) h[j] = 0.0f;
            }
            const int E  = mm ? (e > he ? e : he) : he;
            const int dh = he - E, dn = e - E;
            float g[17];
            #pragma unroll
            for (int j = 0; j < 8; ++j) g[j]     = LDEXP(h[j], dh);
            #pragma unroll
            for (int j = 0; j < 9; ++j) g[8 + j] = LDEXP(f[j], dn);
            e = E;
            __builtin_amdgcn_sched_barrier(0);     // keep ds_reads below shfl use
            // ---- batched pv reads for all 4 steps ----
            float pv[4][9];
            #pragma unroll
            for (int k = 0; k < 4; ++k) {
                const float* rp = &ring[0][sb + k][0];
                #pragma unroll
                for (int j = 0; j < 8; ++j) pv[k][j] = rp[cols[j]] + EPSF;
                pv[k][8] = rp[blank] + EPSF;
            }
            // ---- 4 lane-local stencil sweeps ----
            FWD_SWEEP(pv[0], 2);
            FWD_SWEEP(pv[1], 4);
            FWD_SWEEP(pv[2], 6);
            FWD_SWEEP(pv[3], 8);
            // ---- writeback + renorm ----
            #pragma unroll
            for (int j = 0; j < 9; ++j) f[j] = g[8 + j];
            float mx = f[0];
            #pragma unroll
            for (int j = 1; j < 9; ++j) mx = fmaxf(mx, f[j]);
            const int em = FREXP_EXP(mx);
            #pragma unroll
            for (int j = 0; j < 9; ++j) f[j] = LDEXP(f[j], -em);
            e += em;
            mm = (mx > 0.0f);
            sb  = (sb  == 8) ? 0 : (sb  + 4);
            stb = (stb == 8) ? 0 : (stb + 4);
        }
        // ---- tail: steps t = 1021..1023 (slots 0,1,2) ----
        VMWAIT(4);
        float h[8];
        #pragma unroll
        for (int j = 0; j < 8; ++j) h[j] = __shfl_up(f[j], 1);
        int he = __shfl_up(e, 1);
        if (lane == 0) {
            he = e;
            #pragma unroll
            for (int j = 0; j < 8; ++j) h[j] = 0.0f;
        }
        const int E  = mm ? (e > he ? e : he) : he;
        const int dh = he - E, dn = e - E;
        float g[17];
        #pragma unroll
        for (int j = 0; j < 8; ++j) g[j]     = LDEXP(h[j], dh);
        #pragma unroll
        for (int j = 0; j < 9; ++j) g[8 + j] = LDEXP(f[j], dn);
        e = E;
        __builtin_amdgcn_sched_barrier(0);
        float pv[3][9];
        #pragma unroll
        for (int k = 0; k < 3; ++k) {
            const float* rp = &ring[0][k][0];
            #pragma unroll
            for (int j = 0; j < 8; ++j) pv[k][j] = rp[cols[j]] + EPSF;
            pv[k][8] = rp[blank] + EPSF;
        }
        FWD_SWEEP(pv[0], 4);
        FWD_SWEEP(pv[1], 6);
        FWD_SWEEP(pv[2], 8);
        #pragma unroll
        for (int j = 0; j < 9; ++j) f[j] = g[8 + j];
    } else {
        int sb = 0, stb = 8;
        for (int gI = 0; gI < 255; ++gI) {
            VMWAIT(4);
            #pragma unroll
            for (int k = 0; k < 4; ++k) {
                int ci = 4 * gI + 8 + k; if (ci > 1022) ci = 1022;
                stage16(base + (size_t)(TT - 2 - ci) * CC + 4 * lane,
                        &ring[1][stb + k][0]);
            }
            float h[8];
            #pragma unroll
            for (int j = 0; j < 8; ++j) h[j] = __shfl_down(f[j + 1], 1);
            int he = __shfl_down(e, 1);
            if (lane == 63) {
                he = e;
                #pragma unroll
                for (int j = 0; j < 8; ++j) h[j] = 0.0f;
            }
            const int E  = mm ? (e > he ? e : he) : he;
            const int dh = he - E, dn = e - E;
            float g[17];
            #pragma unroll
            for (int j = 0; j < 9; ++j) g[j]     = LDEXP(f[j], dn);
            #pragma unroll
            for (int j = 0; j < 8; ++j) g[9 + j] = LDEXP(h[j], dh);
            e = E;
            __builtin_amdgcn_sched_barrier(0);
            float pv[4][9];
            #pragma unroll
            for (int k = 0; k < 4; ++k) {
                const float* rp = &ring[1][sb + k][0];
                #pragma unroll
                for (int j = 0; j < 8; ++j) pv[k][j] = rp[cols[j]] + EPSF;
                pv[k][8] = rp[blank] + EPSF;
            }
            BWD_SWEEP(pv[0], 14);
            BWD_SWEEP(pv[1], 12);
            BWD_SWEEP(pv[2], 10);
            BWD_SWEEP(pv[3], 8);
            #pragma unroll
            for (int j = 0; j < 9; ++j) f[j] = g[j];
            float mx = f[0];
            #pragma unroll
            for (int j = 1; j < 9; ++j) mx = fmaxf(mx, f[j]);
            const int em = FREXP_EXP(mx);
            #pragma unroll
            for (int j = 0; j < 9; ++j) f[j] = LDEXP(f[j], -em);
            e += em;
            mm = (mx > 0.0f);
            sb  = (sb  == 8) ? 0 : (sb  + 4);
            stb = (stb == 8) ? 0 : (stb + 4);
        }
        // ---- tail: rows 1026,1025,1024 (slots 0,1,2) ----
        VMWAIT(4);
        float h[8];
        #pragma unroll
        for (int j = 0; j < 8; ++j) h[j] = __shfl_down(f[j + 1], 1);
        int he = __shfl_down(e, 1);
        if (lane == 63) {
            he = e;
            #pragma unroll
            for (int j = 0; j < 8; ++j) h[j] = 0.0f;
        }
        const int E  = mm ? (e > he ? e : he) : he;
        const int dh = he - E, dn = e - E;
        float g[17];
        #pragma unroll
        for (int j = 0; j < 9; ++j) g[j]     = LDEXP(f[j], dn);
        #pragma unroll
        for (int j = 0; j < 8; ++j) g[9 + j] = LDEXP(h[j], dh);
        e = E;
        __builtin_amdgcn_sched_barrier(0);
        float pv[3][9];
        #pragma unroll
        for (int k = 0; k < 3; ++k) {
            const float* rp = &ring[1][k][0];
            #pragma unroll
            for (int j = 0; j < 8; ++j) pv[k][j] = rp[cols[j]] + EPSF;
            pv[k][8] = rp[blank] + EPSF;
        }
        BWD_SWEEP(pv[0], 12);
        BWD_SWEEP(pv[1], 10);
        BWD_SWEEP(pv[2], 8);
        #pragma unroll
        for (int j = 0; j < 9; ++j) f[j] = g[j];

        // combo: beta[TM][s] = g[s] + g[s+1] + allow2[s+2]*g[s+2] (no p mult)
        float d1 = __shfl_down(f[1], 1);
        int   de = __shfl_down(e, 1);
        if (lane == 63) { d1 = 0.0f; de = e; }
        int dlt = de - e;
        if (dlt >= 64) {                           // one-shot, per-lane safe
            #pragma unroll
            for (int j = 0; j < 9; ++j) f[j] = LDEXP(f[j], -dlt);
            e = de; dlt = 0;
        }
        const float bf = LDEXP(d1, dlt);
        float cb[9];
        cb[0] = f[0] + f[1];
        cb[1] = f[1] + f[2] + f[3] * kk[0];
        cb[2] = f[2] + f[3];
        cb[3] = f[3] + f[4] + f[5] * kk[1];
        cb[4] = f[4] + f[5];
        cb[5] = f[5] + f[6] + f[7] * kk[2];
        cb[6] = f[6] + f[7];
        cb[7] = f[7] + f[8] + bf   * kk[3];
        cb[8] = f[8] + bf;                          // combo[512] (lane 63: bf=0)

        #pragma unroll
        for (int j = 0; j < 8; ++j) cw[8 * lane + j] = cb[j];
        if (lane == 63) cw[512] = cb[8];
        ew[lane] = e;
    }

    __syncthreads();

    if (w == 0) {
        // lane l's 8 cells align exactly with bwd lane l's 8 cells
        float part = 0.0f;
        #pragma unroll
        for (int j = 0; j < 8; ++j) part += f[j] * cw[8 * lane + j];
        if (lane == 63) part += f[8] * cw[512];
        int   ep = (part > 0.0f) ? (e + ew[lane]) : EMINI;
        float m  = part;
        #pragma unroll
        for (int d = 1; d < 64; d <<= 1) {
            const float mo = __shfl_xor(m, d);
            const int   eo = __shfl_xor(ep, d);
            const int   E2 = ep > eo ? ep : eo;
            m  = LDEXP(m, ep - E2) + LDEXP(mo, eo - E2);
            ep = E2;
        }
        if (lane == 0)
            out[b] = -LN2F * ((float)ep + __builtin_amdgcn_logf(m));
    }
}

extern "C" void kernel_launch(void* const* d_in, const int* in_sizes, int n_in,
                              void* d_out, int out_size, void* d_ws, size_t ws_size,
                              hipStream_t stream)
{
    const int*   y_true = (const int*)d_in[0];
    const float* y_pred = (const float*)d_in[1];
    float*       out    = (float*)d_out;
    const int B = in_sizes[0] / LL;   // 32
    ctc_grp_kernel<<<B, 128, 0, stream>>>(y_true, y_pred, out);
}

// Round 9
// 205.076 us; speedup vs baseline: 1.3969x; 1.0332x over previous
//
#include <hip/hip_runtime.h>

#define TT   2048
#define CC   256
#define LL   256
#define SS   513            // 2*LL+1
#define TM   1023           // meet point: fwd -> alpha[TM], bwd -> gamma[TM+1]
#define EPSF (1e-7f)
#define LN2F (0.69314718055994531f)
#define DPTH 8              // register prefetch depth (steps ahead)
#define RBTH 64             // rebase threshold (bits)
#define NCH  127            // 127*8 + 7 = 1023 steps
#define EMINI (-2000000000)
#define GSTR 260            // gat row stride (floats): 256 labels + blank + pad

#if __has_builtin(__builtin_amdgcn_frexp_expf)
#define FREXP_EXP __builtin_amdgcn_frexp_expf
#else
static __device__ __forceinline__ int FREXP_EXP(float x){ int e; return (frexpf(x,&e), e); }
#endif
#if __has_builtin(__builtin_amdgcn_ldexpf)
#define LDEXP __builtin_amdgcn_ldexpf
#else
#define LDEXP ldexpf
#endif

// ---------------------------------------------------------------------------
// Pass 1: compact gather. gat[b][t][i] = y_pred[b][t][lab[i]] + eps (i<256),
//         gat[b][t][256] = y_pred[b][t][blank] + eps.
// Thread i owns label slot i; loop over t -> writes coalesced, reads are a
// same-row gather shared by all 4 waves of the block (row L1/L2-resident).
// ---------------------------------------------------------------------------
__launch_bounds__(256, 4)
__global__ void ctc_gather_kernel(const int* __restrict__ y_true,
                                  const float* __restrict__ y_pred,
                                  float* __restrict__ gat)
{
    const int b   = blockIdx.x;
    const int i   = threadIdx.x;                 // 0..255
    const int col = y_true[b * LL + i];
    const float* rp = y_pred + (size_t)b * TT * CC;
    float*       gp = gat    + (size_t)b * TT * GSTR;
    const int tch = TT / gridDim.y;
    const int t0  = blockIdx.y * tch;
    #pragma unroll 4
    for (int t = t0; t < t0 + tch; ++t) {
        gp[(size_t)t * GSTR + i] = rp[(size_t)t * CC + col] + EPSF;
        if (i == 255)
            gp[(size_t)t * GSTR + 256] = rp[(size_t)t * CC + (CC - 1)] + EPSF;
    }
}

// ---------------------------------------------------------------------------
// Pass 2: meet-in-the-middle DP (round-6 structure, compact coalesced loads).
// Block = 128 threads (2 waves) per batch.
//   wave 0: forward alpha DP, rows 1..TM       (init row 0)
//   wave 1: backward gamma DP, rows TT-2..TM+1 (init row TT-1)
// Lane l owns cells s = 8l..8l+7 + shadow f[8] (cell 8(l+1); real 512 on
// lane 63). Even s = blank, odd s = label 4l+i -> ONE float4 gat[t][4l..4l+3]
// + one uniform blank load per step, register-prefetched DPTH deep.
// Extended-range floats: value = f[j]*2^e (one e per lane), renorm every 4.
// ---------------------------------------------------------------------------
__launch_bounds__(128, 1)
__global__ void ctc_fast_kernel(const int* __restrict__ y_true,
                                const float* __restrict__ y_pred,
                                const float* __restrict__ gat,
                                float* __restrict__ out)
{
    __shared__ float cw[SS];   // beta[TM][s] combo mantissas (per-lane scale)
    __shared__ int   ew[64];   // bwd per-lane exponent

    const int tid   = threadIdx.x;
    const int w     = tid >> 6;          // 0 = fwd, 1 = bwd (wave-uniform)
    const int lane  = tid & 63;
    const int b     = blockIdx.x;
    const int blank = CC - 1;

    const int*   lab   = y_true + b * LL;
    const float* base  = y_pred + (size_t)b * TT * CC;
    const float* gbase = gat    + (size_t)b * TT * GSTR;

    // skip-transition legality for the 4 odd cells (label index 4*lane + i)
    int   col0 = lab[4 * lane];
    float kup[4];    // fwd: allow2 into cell s
    float kdn[4];    // bwd: allow2 out of cell s (into s+2)
    #pragma unroll
    for (int i = 0; i < 4; ++i) {
        const int li = 4 * lane + i;               // 0..255
        const int z  = lab[li];
        const int zm = (li >= 1) ? lab[li - 1] : -1;
        kup[i] = (z != zm) ? 1.0f : 0.0f;
        kdn[i] = (li <= 254 && lab[li + 1] != z) ? 1.0f : 0.0f;
    }

    float f[9];
    #pragma unroll
    for (int j = 0; j < 9; ++j) f[j] = 0.0f;
    int  e = 0;
    bool lzero;

    if (w == 0) {
        if (lane == 0) {
            f[0] = base[blank] + EPSF;             // s=0, t=0
            f[1] = base[col0]  + EPSF;             // s=1, t=0
        }
        lzero = (lane != 0);
    } else {
        if (lane == 63) {
            const float* rT = base + (size_t)(TT - 1) * CC;
            f[7] = rT[lab[255]] + EPSF;            // s=511, t=TT-1
            f[8] = rT[blank]    + EPSF;            // s=512 (shadow), t=TT-1
        }
        lzero = (lane != 63);
    }

    // register prefetch ring: one float4 (own 4 label probs) + blank per step
    float4 pf[DPTH];
    float  pbf[DPTH];
    #pragma unroll
    for (int k = 0; k < DPTH; ++k) {
        const int r = (w == 0) ? (1 + k) : (TT - 2 - k);
        const float* rp = gbase + (size_t)r * GSTR;
        pf[k]  = *(const float4*)(rp + 4 * lane);
        pbf[k] = rp[256];
    }

    auto renorm = [&]() {
        float m = fmaxf(fmaxf(fmaxf(f[0], f[1]), fmaxf(f[2], f[3])),
                        fmaxf(fmaxf(f[4], f[5]), fmaxf(f[6], fmaxf(f[7], f[8]))));
        const int em = FREXP_EXP(m);               // frexp_exp(0) == 0
        #pragma unroll
        for (int j = 0; j < 9; ++j) f[j] = LDEXP(f[j], -em);
        e += em;
    };

    auto fwd_step = [&](float pb, float p0, float p1, float p2, float p3) {
        float u7 = __shfl_up(f[7], 1);
        int   ue = __shfl_up(e, 1);
        if (lane == 0) { u7 = 0.0f; ue = e; }
        int dlt = ue - e;
        const bool rb = lzero || (dlt >= RBTH);
        if (__ballot(rb)) {                        // rare: front / scale jump
            const int sh = rb ? -dlt : 0;
            #pragma unroll
            for (int j = 0; j < 9; ++j) f[j] = LDEXP(f[j], sh);
            e   = rb ? ue : e;
            dlt = rb ? 0  : dlt;
            lzero = lzero && (u7 == 0.0f);
        }
        const float bf = LDEXP(u7, dlt);
        const float n0 = (f[0] + bf) * pb;
        const float n1 = (f[1] + f[0] + bf   * kup[0]) * p0;
        const float n2 = (f[2] + f[1]) * pb;
        const float n3 = (f[3] + f[2] + f[1] * kup[1]) * p1;
        const float n4 = (f[4] + f[3]) * pb;
        const float n5 = (f[5] + f[4] + f[3] * kup[2]) * p2;
        const float n6 = (f[6] + f[5]) * pb;
        const float n7 = (f[7] + f[6] + f[5] * kup[3]) * p3;
        const float n8 = (f[8] + f[7]) * pb;
        f[0]=n0; f[1]=n1; f[2]=n2; f[3]=n3; f[4]=n4;
        f[5]=n5; f[6]=n6; f[7]=n7; f[8]=n8;
    };

    auto bwd_step = [&](float pb, float p0, float p1, float p2, float p3) {
        float d1 = __shfl_down(f[1], 1);
        int   de = __shfl_down(e, 1);
        if (lane == 63) { d1 = 0.0f; de = e; }
        int dlt = de - e;
        const bool rb = lzero || (dlt >= RBTH);
        if (__ballot(rb)) {
            const int sh = rb ? -dlt : 0;
            #pragma unroll
            for (int j = 0; j < 9; ++j) f[j] = LDEXP(f[j], sh);
            e   = rb ? de : e;
            dlt = rb ? 0  : dlt;
            lzero = lzero && (d1 == 0.0f);
        }
        const float bf = LDEXP(d1, dlt);
        const float n0 = (f[0] + f[1]) * pb;
        const float n1 = (f[1] + f[2] + f[3] * kdn[0]) * p0;
        const float n2 = (f[2] + f[3]) * pb;
        const float n3 = (f[3] + f[4] + f[5] * kdn[1]) * p1;
        const float n4 = (f[4] + f[5]) * pb;
        const float n5 = (f[5] + f[6] + f[7] * kdn[2]) * p2;
        const float n6 = (f[6] + f[7]) * pb;
        const float n7 = (f[7] + f[8] + bf   * kdn[3]) * p3;
        const float n8 = (f[8] + bf) * pb;
        f[0]=n0; f[1]=n1; f[2]=n2; f[3]=n3; f[4]=n4;
        f[5]=n5; f[6]=n6; f[7]=n7; f[8]=n8;
    };

    if (w == 0) {
        for (int c = 0; c < NCH; ++c) {            // steps t = 1 .. 1016
            #pragma unroll
            for (int k = 0; k < DPTH; ++k) {
                const float pb = pbf[k];
                const float p0 = pf[k].x, p1 = pf[k].y,
                            p2 = pf[k].z, p3 = pf[k].w;
                int tp = 1 + c * DPTH + k + DPTH; if (tp > TM) tp = TM;
                const float* rp = gbase + (size_t)tp * GSTR;
                pf[k]  = *(const float4*)(rp + 4 * lane);
                pbf[k] = rp[256];
                fwd_step(pb, p0, p1, p2, p3);
                if (k == 3 || k == 7) renorm();
            }
        }
        #pragma unroll
        for (int k = 0; k < 7; ++k) {              // tail t = 1017..1023
            fwd_step(pbf[k], pf[k].x, pf[k].y, pf[k].z, pf[k].w);
            if (k == 3) renorm();
        }
    } else {
        for (int c = 0; c < NCH; ++c) {            // rows 2046 down to 1031
            #pragma unroll
            for (int k = 0; k < DPTH; ++k) {
                const float pb = pbf[k];
                const float p0 = pf[k].x, p1 = pf[k].y,
                            p2 = pf[k].z, p3 = pf[k].w;
                int tp = (TT - 2) - (c * DPTH + k) - DPTH;
                if (tp < TM + 1) tp = TM + 1;
                const float* rp = gbase + (size_t)tp * GSTR;
                pf[k]  = *(const float4*)(rp + 4 * lane);
                pbf[k] = rp[256];
                bwd_step(pb, p0, p1, p2, p3);
                if (k == 3 || k == 7) renorm();
            }
        }
        #pragma unroll
        for (int k = 0; k < 7; ++k) {              // rows 1030..1024
            bwd_step(pbf[k], pf[k].x, pf[k].y, pf[k].z, pf[k].w);
            if (k == 3) renorm();
        }

        // combo: beta[TM][s] = g[s] + g[s+1] + allow2[s+2]*g[s+2] (no p mult)
        float d1 = __shfl_down(f[1], 1);
        int   de = __shfl_down(e, 1);
        if (lane == 63) { d1 = 0.0f; de = e; }
        int dlt = de - e;
        if (dlt >= RBTH) {                         // one-shot, per-lane safe
            #pragma unroll
            for (int j = 0; j < 9; ++j) f[j] = LDEXP(f[j], -dlt);
            e = de; dlt = 0;
        }
        const float bf = LDEXP(d1, dlt);
        float cb[9];
        cb[0] = f[0] + f[1];
        cb[1] = f[1] + f[2] + f[3] * kdn[0];
        cb[2] = f[2] + f[3];
        cb[3] = f[3] + f[4] + f[5] * kdn[1];
        cb[4] = f[4] + f[5];
        cb[5] = f[5] + f[6] + f[7] * kdn[2];
        cb[6] = f[6] + f[7];
        cb[7] = f[7] + f[8] + bf   * kdn[3];
        cb[8] = f[8] + bf;                          // combo[512] (lane 63: bf=0)

        #pragma unroll
        for (int j = 0; j < 8; ++j) cw[8 * lane + j] = cb[j];
        if (lane == 63) cw[512] = cb[8];
        ew[lane] = e;
    }

    __syncthreads();

    if (w == 0) {
        // lane l's 8 cells align exactly with bwd lane l's 8 cells
        float part = 0.0f;
        #pragma unroll
        for (int j = 0; j < 8; ++j) part += f[j] * cw[8 * lane + j];
        if (lane == 63) part += f[8] * cw[512];
        int   ep = (part > 0.0f) ? (e + ew[lane]) : EMINI;
        float m  = part;
        #pragma unroll
        for (int d = 1; d < 64; d <<= 1) {
            const float mo = __shfl_xor(m, d);
            const int   eo = __shfl_xor(ep, d);
            const int   E  = ep > eo ? ep : eo;
            m  = LDEXP(m, ep - E) + LDEXP(mo, eo - E);
            ep = E;
        }
        if (lane == 0)
            out[b] = -LN2F * ((float)ep + __builtin_amdgcn_logf(m));
    }
}

// ---------------------------------------------------------------------------
// Fallback (round-6 verbatim, proven): used only if ws_size is too small.
// ---------------------------------------------------------------------------
__launch_bounds__(128, 1)
__global__ void ctc_fb_kernel(const int* __restrict__ y_true,
                              const float* __restrict__ y_pred,
                              float* __restrict__ out)
{
    __shared__ float cw[SS];
    __shared__ int   ew[64];

    const int tid   = threadIdx.x;
    const int w     = tid >> 6;
    const int lane  = tid & 63;
    const int b     = blockIdx.x;
    const int blank = CC - 1;

    const int*   lab  = y_true + b * LL;
    const float* base = y_pred + (size_t)b * TT * CC;

    int   col[4];
    float kup[4], kdn[4];
    #pragma unroll
    for (int i = 0; i < 4; ++i) {
        const int li = 4 * lane + i;
        const int z  = lab[li];
        col[i] = z;
        const int zm = (li >= 1) ? lab[li - 1] : -1;
        kup[i] = (z != zm) ? 1.0f : 0.0f;
        kdn[i] = (li <= 254 && lab[li + 1] != z) ? 1.0f : 0.0f;
    }

    float f[9];
    #pragma unroll
    for (int j = 0; j < 9; ++j) f[j] = 0.0f;
    int  e = 0;
    bool lzero;

    if (w == 0) {
        if (lane == 0) { f[0] = base[blank] + EPSF; f[1] = base[col[0]] + EPSF; }
        lzero = (lane != 0);
    } else {
        if (lane == 63) {
            const float* rT = base + (size_t)(TT - 1) * CC;
            f[7] = rT[col[3]] + EPSF; f[8] = rT[blank] + EPSF;
        }
        lzero = (lane != 63);
    }

    float pfb[DPTH]; float pfl[DPTH][4];
    #pragma unroll
    for (int k = 0; k < DPTH; ++k) {
        const int r = (w == 0) ? (1 + k) : (TT - 2 - k);
        const float* rp = base + (size_t)r * CC;
        pfb[k] = rp[blank];
        #pragma unroll
        for (int i = 0; i < 4; ++i) pfl[k][i] = rp[col[i]];
    }

    auto renorm = [&]() {
        float m = fmaxf(fmaxf(fmaxf(f[0], f[1]), fmaxf(f[2], f[3])),
                        fmaxf(fmaxf(f[4], f[5]), fmaxf(f[6], fmaxf(f[7], f[8]))));
        const int em = FREXP_EXP(m);
        #pragma unroll
        for (int j = 0; j < 9; ++j) f[j] = LDEXP(f[j], -em);
        e += em;
    };
    auto fwd_step = [&](float pb, float p0, float p1, float p2, float p3) {
        float u7 = __shfl_up(f[7], 1);
        int   ue = __shfl_up(e, 1);
        if (lane == 0) { u7 = 0.0f; ue = e; }
        int dlt = ue - e;
        const bool rb = lzero || (dlt >= RBTH);
        if (__ballot(rb)) {
            const int sh = rb ? -dlt : 0;
            #pragma unroll
            for (int j = 0; j < 9; ++j) f[j] = LDEXP(f[j], sh);
            e = rb ? ue : e; dlt = rb ? 0 : dlt;
            lzero = lzero && (u7 == 0.0f);
        }
        const float bf = LDEXP(u7, dlt);
        const float n0 = (f[0] + bf) * pb;
        const float n1 = (f[1] + f[0] + bf   * kup[0]) * p0;
        const float n2 = (f[2] + f[1]) * pb;
        const float n3 = (f[3] + f[2] + f[1] * kup[1]) * p1;
        const float n4 = (f[4] + f[3]) * pb;
        const float n5 = (f[5] + f[4] + f[3] * kup[2]) * p2;
        const float n6 = (f[6] + f[5]) * pb;
        const float n7 = (f[7] + f[6] + f[5] * kup[3]) * p3;
        const float n8 = (f[8] + f[7]) * pb;
        f[0]=n0; f[1]=n1; f[2]=n2; f[3]=n3; f[4]=n4;
        f[5]=n5; f[6]=n6; f[7]=n7; f[8]=n8;
    };
    auto bwd_step = [&](float pb, float p0, float p1, float p2, float p3) {
        float d1 = __shfl_down(f[1], 1);
        int   de = __shfl_down(e, 1);
        if (lane == 63) { d1 = 0.0f; de = e; }
        int dlt = de - e;
        const bool rb = lzero || (dlt >= RBTH);
        if (__ballot(rb)) {
            const int sh = rb ? -dlt : 0;
            #pragma unroll
            for (int j = 0; j < 9; ++j) f[j] = LDEXP(f[j], sh);
            e = rb ? de : e; dlt = rb ? 0 : dlt;
            lzero = lzero && (d1 == 0.0f);
        }
        const float bf = LDEXP(d1, dlt);
        const float n0 = (f[0] + f[1]) * pb;
        const float n1 = (f[1] + f[2] + f[3] * kdn[0]) * p0;
        const float n2 = (f[2] + f[3]) * pb;
        const float n3 = (f[3] + f[4] + f[5] * kdn[1]) * p1;
        const float n4 = (f[4] + f[5]) * pb;
        const float n5 = (f[5] + f[6] + f[7] * kdn[2]) * p2;
        const float n6 = (f[6] + f[7]) * pb;
        const float n7 = (f[7] + f[8] + bf   * kdn[3]) * p3;
        const float n8 = (f[8] + bf) * pb;
        f[0]=n0; f[1]=n1; f[2]=n2; f[3]=n3; f[4]=n4;
        f[5]=n5; f[6]=n6; f[7]=n7; f[8]=n8;
    };

    if (w == 0) {
        for (int c = 0; c < NCH; ++c) {
            #pragma unroll
            for (int k = 0; k < DPTH; ++k) {
                const float pb = pfb[k] + EPSF;
                const float p0 = pfl[k][0] + EPSF, p1 = pfl[k][1] + EPSF;
                const float p2 = pfl[k][2] + EPSF, p3 = pfl[k][3] + EPSF;
                int tp = 1 + c * DPTH + k + DPTH; if (tp > TM) tp = TM;
                const float* rp = base + (size_t)tp * CC;
                pfb[k] = rp[blank];
                #pragma unroll
                for (int i = 0; i < 4; ++i) pfl[k][i] = rp[col[i]];
                fwd_step(pb, p0, p1, p2, p3);
                if (k == 3 || k == 7) renorm();
            }
        }
        #pragma unroll
        for (int k = 0; k < 7; ++k) {
            fwd_step(pfb[k] + EPSF, pfl[k][0] + EPSF, pfl[k][1] + EPSF,
                     pfl[k][2] + EPSF, pfl[k][3] + EPSF);
            if (k == 3) renorm();
        }
    } else {
        for (int c = 0; c < NCH; ++c) {
            #pragma unroll
            for (int k = 0; k < DPTH; ++k) {
                const float pb = pfb[k] + EPSF;
                const float p0 = pfl[k][0] + EPSF, p1 = pfl[k][1] + EPSF;
                const float p2 = pfl[k][2] + EPSF, p3 = pfl[k][3] + EPSF;
                int tp = (TT - 2) - (c * DPTH + k) - DPTH; if (tp < TM + 1) tp = TM + 1;
                const float* rp = base + (size_t)tp * CC;
                pfb[k] = rp[blank];
                #pragma unroll
                for (int i = 0; i < 4; ++i) pfl[k][i] = rp[col[i]];
                bwd_step(pb, p0, p1, p2, p3);
                if (k == 3 || k == 7) renorm();
            }
        }
        #pragma unroll
        for (int k = 0; k < 7; ++k) {
            bwd_step(pfb[k] + EPSF, pfl[k][0] + EPSF, pfl[k][1] + EPSF,
                     pfl[k][2] + EPSF, pfl[k][3] + EPSF);
            if (k == 3) renorm();
        }

        float d1 = __shfl_down(f[1], 1);
        int   de = __shfl_down(e, 1);
        if (lane == 63) { d1 = 0.0f; de = e; }
        int dlt = de - e;
        if (dlt >= RBTH) {
            #pragma unroll
            for (int j = 0; j < 9; ++j) f[j] = LDEXP(f[j], -dlt);
            e = de; dlt = 0;
        }
        const float bf = LDEXP(d1, dlt);
        float cb[9];
        cb[0] = f[0] + f[1];
        cb[1] = f[1] + f[2] + f[3] * kdn[0];
        cb[2] = f[2] + f[3];
        cb[3] = f[3] + f[4] + f[5] * kdn[1];
        cb[4] = f[4] + f[5];
        cb[5] = f[5] + f[6] + f[7] * kdn[2];
        cb[6] = f[6] + f[7];
        cb[7] = f[7] + f[8] + bf   * kdn[3];
        cb[8] = f[8] + bf;
        #pragma unroll
        for (int j = 0; j < 8; ++j) cw[8 * lane + j] = cb[j];
        if (lane == 63) cw[512] = cb[8];
        ew[lane] = e;
    }

    __syncthreads();

    if (w == 0) {
        float part = 0.0f;
        #pragma unroll
        for (int j = 0; j < 8; ++j) part += f[j] * cw[8 * lane + j];
        if (lane == 63) part += f[8] * cw[512];
        int   ep = (part > 0.0f) ? (e + ew[lane]) : EMINI;
        float m  = part;
        #pragma unroll
        for (int d = 1; d < 64; d <<= 1) {
            const float mo = __shfl_xor(m, d);
            const int   eo = __shfl_xor(ep, d);
            const int   E  = ep > eo ? ep : eo;
            m  = LDEXP(m, ep - E) + LDEXP(mo, eo - E);
            ep = E;
        }
        if (lane == 0)
            out[b] = -LN2F * ((float)ep + __builtin_amdgcn_logf(m));
    }
}

extern "C" void kernel_launch(void* const* d_in, const int* in_sizes, int n_in,
                              void* d_out, int out_size, void* d_ws, size_t ws_size,
                              hipStream_t stream)
{
    const int*   y_true = (const int*)d_in[0];
    const float* y_pred = (const float*)d_in[1];
    float*       out    = (float*)d_out;
    const int B = in_sizes[0] / LL;   // 32

    const size_t need = (size_t)B * TT * GSTR * sizeof(float);  // ~68.2 MB
    if (ws_size >= need) {
        float* gat = (float*)d_ws;
        ctc_gather_kernel<<<dim3(B, 32), 256, 0, stream>>>(y_true, y_pred, gat);
        ctc_fast_kernel<<<B, 128, 0, stream>>>(y_true, y_pred, gat, out);
    } else {
        ctc_fb_kernel<<<B, 128, 0, stream>>>(y_true, y_pred, out);
    }
}